// Round 3
// baseline (71.274 us; speedup 1.0000x reference)
//
#include <hip/hip_runtime.h>
#include <stdint.h>

typedef unsigned short u16;
typedef unsigned int u32;
typedef __attribute__((ext_vector_type(8))) __bf16 bf16x8;
typedef __attribute__((ext_vector_type(4))) float f32x4;

#define B_TOT   32768
#define T_SEQ   96
#define D_IN    7
#define K_LIN   288   // H*T
#define N_LIN   672   // O*T
#define N_PAD   768   // padded N so 128-wide tiles need no load guards

// ---------- helpers ----------
__device__ __forceinline__ u16 f2bf(float f) {
  u32 u = __builtin_bit_cast(u32, f);
  u += 0x7fffu + ((u >> 16) & 1u);   // RNE; inputs finite
  return (u16)(u >> 16);
}
__device__ __forceinline__ float fast_sig(float z) {
  return __builtin_amdgcn_rcpf(1.0f + __expf(-z));
}
__device__ __forceinline__ float fast_tanh(float z) {
  // tanh(z) = 1 - 2/(1+e^{2z}); stable at both tails
  return 1.0f - 2.0f * __builtin_amdgcn_rcpf(1.0f + __expf(2.0f * z));
}
// broadcast quad-lane Q's value to all 4 lanes of the quad (DPP, full-rate VALU)
template<int Q>
__device__ __forceinline__ float qbcast(float v) {
  int i = __builtin_bit_cast(int, v);
  i = __builtin_amdgcn_update_dpp(0, i, Q * 0x55, 0xF, 0xF, true);
  return __builtin_bit_cast(float, i);
}

// ---------- kernel 1: pad/convert W_lin -> bf16, k-permuted to j-major ----------
// Bw[n][j*96+t] = Wlin[n][t*3+j]  (matches lstm's j-major hs layout)
__global__ __launch_bounds__(256) void convert_kernel(
    const float* __restrict__ Wlin, const float* __restrict__ blin,
    u16* __restrict__ Bw, float* __restrict__ biasp)
{
  int i = blockIdx.x * 256 + threadIdx.x;
  if (i < N_PAD * K_LIN) {
    int n = i / K_LIN;
    int kk = i - n * K_LIN;
    int jm = kk / T_SEQ;          // 0..2
    int tm = kk - jm * T_SEQ;     // 0..95
    Bw[i] = f2bf((n < N_LIN) ? Wlin[n * K_LIN + tm * 3 + jm] : 0.0f);
  }
  if (i < N_PAD) biasp[i] = (i < N_LIN) ? blin[i] : 0.0f;
}

// ---------- kernel 2: LSTM, 4 lanes per chain (lane q -> unit j=min(q,2)) ----------
__device__ __forceinline__ void chunk4(
    const float* xc,
    float& h0, float& h1, float& h2, float& c,
    const float (&wih)[4][7], const float (&whh)[4][3], const float (&bias)[4],
    u16* pk)
{
  // h-independent pre-activations for all 4 steps: 112 independent FMAs of ILP
  float zx[4][4];
#pragma unroll
  for (int s = 0; s < 4; ++s) {
#pragma unroll
    for (int G = 0; G < 4; ++G) {
      float a = bias[G];
#pragma unroll
      for (int k = 0; k < 7; ++k) a = fmaf(xc[s * 7 + k], wih[G][k], a);
      zx[s][G] = a;
    }
  }
#pragma unroll
  for (int s = 0; s < 4; ++s) {
    float zi = fmaf(h2, whh[0][2], fmaf(h1, whh[0][1], fmaf(h0, whh[0][0], zx[s][0])));
    float zf = fmaf(h2, whh[1][2], fmaf(h1, whh[1][1], fmaf(h0, whh[1][0], zx[s][1])));
    float zg = fmaf(h2, whh[2][2], fmaf(h1, whh[2][1], fmaf(h0, whh[2][0], zx[s][2])));
    float zo = fmaf(h2, whh[3][2], fmaf(h1, whh[3][1], fmaf(h0, whh[3][0], zx[s][3])));
    float ig = fast_sig(zi);
    float fg = fast_sig(zf);
    float gg = fast_tanh(zg);
    float og = fast_sig(zo);
    c = fmaf(fg, c, ig * gg);
    float hv = og * fast_tanh(c);
    pk[s] = f2bf(hv);
    h0 = qbcast<0>(hv);
    h1 = qbcast<1>(hv);
    h2 = qbcast<2>(hv);
  }
}

// (256, 2): min 2 waves/SIMD -> VGPR cap 256. Live state ~134 regs; the
// default heuristic capped at 60 VGPR and spilled to scratch (round-2 PMC:
// WRITE_SIZE 56MB vs 19MB of real output). Grid is 2048 waves = 2/SIMD, so
// 256 VGPRs cost zero occupancy.
__global__ __launch_bounds__(256, 2) void lstm_kernel(
    const float* __restrict__ x,
    const float* __restrict__ Wih, const float* __restrict__ Whh,
    const float* __restrict__ bih, const float* __restrict__ bhh,
    u16* __restrict__ hs)
{
  __shared__ float sW[132];
  const int tid = threadIdx.x;
  for (int i = tid; i < 132; i += 256) {
    float v;
    if (i < 84)       v = Wih[i];
    else if (i < 120) v = Whh[i - 84];
    else              v = bih[i - 120] + bhh[i - 120];
    sW[i] = v;
  }
  __syncthreads();

  const int j  = tid & 3;
  const int jj = (j < 3) ? j : 2;   // lane 3 mirrors lane 2 (never stores)

  // per-lane weights: 4 gates (i,f,g,o) for unit jj; constant-indexed => registers
  float wih[4][7], whh[4][3], bias[4];
#pragma unroll
  for (int G = 0; G < 4; ++G) {
    const int row = G * 3 + jj;     // W_ih rows: gate G, unit jj
#pragma unroll
    for (int k = 0; k < 7; ++k) wih[G][k] = sW[row * 7 + k];
#pragma unroll
    for (int m = 0; m < 3; ++m) whh[G][m] = sW[84 + row * 3 + m];
    bias[G] = sW[120 + row];
  }

  const int b = (blockIdx.x * 256 + tid) >> 2;
  const float4* __restrict__ xr = (const float4*)(x + (size_t)b * (T_SEQ * D_IN));
  u16* __restrict__ hrow = hs + (size_t)b * K_LIN + jj * T_SEQ;  // j-major

  float h0 = 0.f, h1 = 0.f, h2 = 0.f, c = 0.f;
  float xa[28] __attribute__((aligned(16)));   // 4 timesteps (112B, 16B-aligned chunks)
  float xb[28] __attribute__((aligned(16)));
  u16 pk[8] __attribute__((aligned(16)));      // 8 steps of this lane's h, bf16

#pragma unroll
  for (int q = 0; q < 7; ++q) ((float4*)xa)[q] = xr[q];

#pragma unroll 1
  for (int g8 = 0; g8 < 12; ++g8) {            // 8 steps per iter
#pragma unroll
    for (int q = 0; q < 7; ++q) ((float4*)xb)[q] = xr[(2 * g8 + 1) * 7 + q];
    chunk4(xa, h0, h1, h2, c, wih, whh, bias, pk);
    if (g8 < 11) {
#pragma unroll
      for (int q = 0; q < 7; ++q) ((float4*)xa)[q] = xr[(2 * g8 + 2) * 7 + q];
    }
    chunk4(xb, h0, h1, h2, c, wih, whh, bias, pk + 4);
    if (j < 3) {
      // 8 bf16 = 16B, contiguous in t (j-major layout), 16B-aligned
      *(uint4*)(hrow + g8 * 8) = *(const uint4*)pk;
    }
  }
}

// ---------- kernel 3: out = hs(bf16)[32768x288] x Bw^T(bf16)[768x288] + bias ----------
__device__ __forceinline__ void gload16(const u16* g, u16* l) {
  __builtin_amdgcn_global_load_lds(
      (const __attribute__((address_space(1))) void*)g,
      (__attribute__((address_space(3))) void*)l, 16, 0, 0);
}

__global__ __launch_bounds__(256) void gemm_kernel(
    const u16* __restrict__ A, const u16* __restrict__ Bw,
    const float* __restrict__ bias, float* __restrict__ C)
{
  __shared__ u16 As[128 * 32];   // 8KB, row-major [128][32]
  __shared__ u16 Bs[128 * 32];
  const int tid  = threadIdx.x;
  const int lane = tid & 63;
  const int wid  = tid >> 6;
  const int wm = wid >> 1, wn = wid & 1;   // 2x2 waves of 64x64

  // XCD-bijective swizzle (1536 % 8 == 0); consecutive swz share A row-panel
  int bx = blockIdx.x;
  int swz = (bx & 7) * 192 + (bx >> 3);
  const int bm = swz / 6;
  const int bn = swz - bm * 6;
  const size_t m0 = (size_t)bm * 128;
  const int n0 = bn * 128;

  const int ra = tid >> 2;          // row 0..63 within half-tile
  const int ca = (tid & 3) * 8;     // 8 bf16 = 16B per thread
  const u16* ga = A  + (m0 + (size_t)ra) * K_LIN + ca;
  const u16* gb = Bw + (size_t)(n0 + ra) * K_LIN + ca;
  u16* lA = &As[wid * 512];         // wave-uniform base; HW adds lane*16B
  u16* lB = &Bs[wid * 512];

  const int l15 = lane & 15, l4 = lane >> 4;
  const u16* pAf = &As[(wm * 64 + l15) * 32 + l4 * 8];
  const u16* pBf = &Bs[(wn * 64 + l15) * 32 + l4 * 8];

  f32x4 acc[4][4] = {};

  for (int kt = 0; kt < 9; ++kt) {  // K = 288 = 9*32
    const int ko = kt * 32;
    gload16(ga + ko,               lA);
    gload16(ga + 64 * K_LIN + ko,  lA + 2048);
    gload16(gb + ko,               lB);
    gload16(gb + 64 * K_LIN + ko,  lB + 2048);
    __syncthreads();                 // drains vmcnt(0) -> tiles resident
    bf16x8 af[4], bfv[4];
#pragma unroll
    for (int i = 0; i < 4; ++i) af[i]  = *(const bf16x8*)(const void*)(pAf + i * 512);
#pragma unroll
    for (int i = 0; i < 4; ++i) bfv[i] = *(const bf16x8*)(const void*)(pBf + i * 512);
#pragma unroll
    for (int mi = 0; mi < 4; ++mi)
#pragma unroll
      for (int ni = 0; ni < 4; ++ni)
        acc[mi][ni] = __builtin_amdgcn_mfma_f32_16x16x32_bf16(af[mi], bfv[ni], acc[mi][ni], 0, 0, 0);
    __syncthreads();                 // protect LDS before next stage
  }

  float bv[4];
#pragma unroll
  for (int ni = 0; ni < 4; ++ni) bv[ni] = bias[n0 + wn * 64 + ni * 16 + l15];

#pragma unroll
  for (int mi = 0; mi < 4; ++mi) {
#pragma unroll
    for (int ni = 0; ni < 4; ++ni) {
      const int col = n0 + wn * 64 + ni * 16 + l15;
      if (col < N_LIN) {
#pragma unroll
        for (int r = 0; r < 4; ++r) {
          const size_t row = m0 + wm * 64 + mi * 16 + l4 * 4 + r;
          C[row * N_LIN + col] = acc[mi][ni][r] + bv[ni];
        }
      }
    }
  }
}

extern "C" void kernel_launch(void* const* d_in, const int* in_sizes, int n_in,
                              void* d_out, int out_size, void* d_ws, size_t ws_size,
                              hipStream_t stream) {
  const float* x    = (const float*)d_in[0];
  const float* Wih  = (const float*)d_in[1];
  const float* Whh  = (const float*)d_in[2];
  const float* bih  = (const float*)d_in[3];
  const float* bhh  = (const float*)d_in[4];
  const float* Wlin = (const float*)d_in[5];
  const float* blin = (const float*)d_in[6];
  float* out = (float*)d_out;

  // workspace layout (19.3 MB): hs bf16 [32768][288] | Bw bf16 [768][288] | bias f32 [768]
  u16* hs = (u16*)d_ws;
  u16* Bw = (u16*)((char*)d_ws + (size_t)B_TOT * K_LIN * 2);
  float* biasp = (float*)((char*)d_ws + (size_t)B_TOT * K_LIN * 2 + (size_t)N_PAD * K_LIN * 2);

  convert_kernel<<<(N_PAD * K_LIN + 255) / 256, 256, 0, stream>>>(Wlin, blin, Bw, biasp);
  lstm_kernel<<<(B_TOT * 4) / 256, 256, 0, stream>>>(x, Wih, Whh, bih, bhh, hs);
  gemm_kernel<<<(B_TOT / 128) * (N_PAD / 128), 256, 0, stream>>>(hs, Bw, biasp, out);
}

// Round 4
// 69.623 us; speedup vs baseline: 1.0237x; 1.0237x over previous
//
#include <hip/hip_runtime.h>
#include <stdint.h>

typedef unsigned short u16;
typedef unsigned int u32;
typedef __attribute__((ext_vector_type(8))) __bf16 bf16x8;
typedef __attribute__((ext_vector_type(4))) float f32x4;

#define B_TOT   32768
#define T_SEQ   96
#define D_IN    7
#define K_LIN   288   // H*T
#define N_LIN   672   // O*T
#define N_PAD   768   // padded N so 128-wide tiles need no load guards

#define LOG2E      1.4426950408889634f
#define TWO_LOG2E  2.8853900817779268f

// ---------- helpers ----------
__device__ __forceinline__ u16 f2bf(float f) {
  u32 u = __builtin_bit_cast(u32, f);
  u += 0x7fffu + ((u >> 16) & 1u);   // RNE; inputs finite
  return (u16)(u >> 16);
}
// z' = z*log2e prescaled:  sigmoid(z) = rcp(1 + 2^(-z'))
__device__ __forceinline__ float sig2(float zp) {
  return __builtin_amdgcn_rcpf(1.0f + __builtin_amdgcn_exp2f(-zp));
}
// z'' = 2*log2e*z prescaled:  tanh(z) = 1 - 2*rcp(1 + 2^(z''))
__device__ __forceinline__ float tanh2(float zpp) {
  return 1.0f - 2.0f * __builtin_amdgcn_rcpf(1.0f + __builtin_amdgcn_exp2f(zpp));
}
// broadcast quad-lane Q's value to all 4 lanes of the quad (DPP, full-rate VALU)
template<int Q>
__device__ __forceinline__ float qbcast(float v) {
  int i = __builtin_bit_cast(int, v);
  i = __builtin_amdgcn_update_dpp(0, i, Q * 0x55, 0xF, 0xF, true);
  return __builtin_bit_cast(float, i);
}

// ---------- kernel 1: pad/convert W_lin -> bf16, k-permuted to j-major ----------
// Bw[n][j*96+t] = Wlin[n][t*3+j]  (matches lstm's j-major hs layout)
__global__ __launch_bounds__(256) void convert_kernel(
    const float* __restrict__ Wlin, const float* __restrict__ blin,
    u16* __restrict__ Bw, float* __restrict__ biasp)
{
  int i = blockIdx.x * 256 + threadIdx.x;
  if (i < N_PAD * K_LIN) {
    int n = i / K_LIN;
    int kk = i - n * K_LIN;
    int jm = kk / T_SEQ;          // 0..2
    int tm = kk - jm * T_SEQ;     // 0..95
    Bw[i] = f2bf((n < N_LIN) ? Wlin[n * K_LIN + tm * 3 + jm] : 0.0f);
  }
  if (i < N_PAD) biasp[i] = (i < N_LIN) ? blin[i] : 0.0f;
}

// ---------- kernel 2: LSTM, 4 lanes per chain (lane q -> unit j=min(q,2)) ----------
__device__ __forceinline__ void chunk4(
    const float* xc,
    float& h0, float& h1, float& h2, float& c,
    const float (&wih)[4][7], const float (&whh)[4][3], const float (&bias)[4],
    float* hv_out)
{
  // h-independent pre-activations for all 4 steps: 112 independent FMAs of ILP
  float zx[4][4];
#pragma unroll
  for (int s = 0; s < 4; ++s) {
#pragma unroll
    for (int G = 0; G < 4; ++G) {
      float a = bias[G];
#pragma unroll
      for (int k = 0; k < 7; ++k) a = fmaf(xc[s * 7 + k], wih[G][k], a);
      zx[s][G] = a;
    }
  }
#pragma unroll
  for (int s = 0; s < 4; ++s) {
    float zi = fmaf(h2, whh[0][2], fmaf(h1, whh[0][1], fmaf(h0, whh[0][0], zx[s][0])));
    float zf = fmaf(h2, whh[1][2], fmaf(h1, whh[1][1], fmaf(h0, whh[1][0], zx[s][1])));
    float zg = fmaf(h2, whh[2][2], fmaf(h1, whh[2][1], fmaf(h0, whh[2][0], zx[s][2])));
    float zo = fmaf(h2, whh[3][2], fmaf(h1, whh[3][1], fmaf(h0, whh[3][0], zx[s][3])));
    float ig = sig2(zi);
    float fg = sig2(zf);
    float gg = tanh2(zg);                 // g-row prescaled by 2*log2e
    float og = sig2(zo);
    c = fmaf(fg, c, ig * gg);
    float hv = og * tanh2(c * TWO_LOG2E);
    hv_out[s] = hv;
    h0 = qbcast<0>(hv);
    h1 = qbcast<1>(hv);
    h2 = qbcast<2>(hv);
  }
}

// waves_per_eu(2,2): grid is exactly 2 waves/SIMD, so cap=2 is free and the
// RA budget becomes 256 VGPR. Rounds 2-3 showed the default heuristic pins
// VGPR=60 and sinks weight ds_reads into the serial chain (55us, WRITE 56MB
// scratch). Weights are additionally asm-pinned below so they CANNOT be
// rematerialized from LDS inside the loop.
__global__ __attribute__((amdgpu_flat_work_group_size(256, 256), amdgpu_waves_per_eu(2, 2)))
void lstm_kernel(
    const float* __restrict__ x,
    const float* __restrict__ Wih, const float* __restrict__ Whh,
    const float* __restrict__ bih, const float* __restrict__ bhh,
    u16* __restrict__ hs)
{
  __shared__ float sW[132];
  const int tid = threadIdx.x;
  for (int i = tid; i < 132; i += 256) {
    float v; int row;
    if (i < 84)       { v = Wih[i];       row = i / 7; }
    else if (i < 120) { v = Whh[i - 84];  row = (i - 84) / 3; }
    else              { v = bih[i - 120] + bhh[i - 120]; row = i - 120; }
    const int G = row / 3;                 // gate 0..3 (i,f,g,o)
    sW[i] = v * ((G == 2) ? TWO_LOG2E : LOG2E);
  }
  __syncthreads();

  const int j  = tid & 3;
  const int jj = (j < 3) ? j : 2;   // lane 3 mirrors lane 2 (never stores)

  // per-lane weights: 4 gates (i,f,g,o) for unit jj
  float wih[4][7], whh[4][3], bias[4];
#pragma unroll
  for (int G = 0; G < 4; ++G) {
    const int row = G * 3 + jj;
#pragma unroll
    for (int k = 0; k < 7; ++k) wih[G][k] = sW[row * 7 + k];
#pragma unroll
    for (int m = 0; m < 3; ++m) whh[G][m] = sW[84 + row * 3 + m];
    bias[G] = sW[120 + row];
  }
  // pin in VGPRs: opaque asm makes remat/sinking of the LDS loads impossible
#pragma unroll
  for (int G = 0; G < 4; ++G) {
#pragma unroll
    for (int k = 0; k < 7; ++k) asm volatile("" : "+v"(wih[G][k]));
#pragma unroll
    for (int m = 0; m < 3; ++m) asm volatile("" : "+v"(whh[G][m]));
    asm volatile("" : "+v"(bias[G]));
  }

  const int b = (blockIdx.x * 256 + tid) >> 2;
  const float4* __restrict__ xr = (const float4*)(x + (size_t)b * (T_SEQ * D_IN));
  u16* __restrict__ hrow = hs + (size_t)b * K_LIN + jj * T_SEQ;  // j-major

  float h0 = 0.f, h1 = 0.f, h2 = 0.f, c = 0.f;
  float xa[28] __attribute__((aligned(16)));   // 4 timesteps
  float xb[28] __attribute__((aligned(16)));
  float hv8[8];                                 // 8 steps of this lane's h, f32

#pragma unroll
  for (int q = 0; q < 7; ++q) ((float4*)xa)[q] = xr[q];

#pragma unroll 1
  for (int g8 = 0; g8 < 12; ++g8) {            // 8 steps per iter
#pragma unroll
    for (int q = 0; q < 7; ++q) ((float4*)xb)[q] = xr[(2 * g8 + 1) * 7 + q];
    chunk4(xa, h0, h1, h2, c, wih, whh, bias, hv8);
    if (g8 < 11) {
#pragma unroll
      for (int q = 0; q < 7; ++q) ((float4*)xa)[q] = xr[(2 * g8 + 2) * 7 + q];
    }
    chunk4(xb, h0, h1, h2, c, wih, whh, bias, hv8 + 4);
    if (j < 3) {
      u32 w0, w1, w2, w3;
      asm("v_cvt_pk_bf16_f32 %0, %1, %2" : "=v"(w0) : "v"(hv8[0]), "v"(hv8[1]));
      asm("v_cvt_pk_bf16_f32 %0, %1, %2" : "=v"(w1) : "v"(hv8[2]), "v"(hv8[3]));
      asm("v_cvt_pk_bf16_f32 %0, %1, %2" : "=v"(w2) : "v"(hv8[4]), "v"(hv8[5]));
      asm("v_cvt_pk_bf16_f32 %0, %1, %2" : "=v"(w3) : "v"(hv8[6]), "v"(hv8[7]));
      uint4 pkv; pkv.x = w0; pkv.y = w1; pkv.z = w2; pkv.w = w3;
      *(uint4*)(hrow + g8 * 8) = pkv;          // 16B, contiguous in t (j-major)
    }
  }
}

// ---------- kernel 3: out = hs(bf16)[32768x288] x Bw^T(bf16)[768x288] + bias ----------
__device__ __forceinline__ void gload16(const u16* g, u16* l) {
  __builtin_amdgcn_global_load_lds(
      (const __attribute__((address_space(1))) void*)g,
      (__attribute__((address_space(3))) void*)l, 16, 0, 0);
}

__global__ __launch_bounds__(256) void gemm_kernel(
    const u16* __restrict__ A, const u16* __restrict__ Bw,
    const float* __restrict__ bias, float* __restrict__ C)
{
  __shared__ u16 As[128 * 32];   // 8KB, row-major [128][32]
  __shared__ u16 Bs[128 * 32];
  const int tid  = threadIdx.x;
  const int lane = tid & 63;
  const int wid  = tid >> 6;
  const int wm = wid >> 1, wn = wid & 1;   // 2x2 waves of 64x64

  // XCD-bijective swizzle (1536 % 8 == 0); consecutive swz share A row-panel
  int bx = blockIdx.x;
  int swz = (bx & 7) * 192 + (bx >> 3);
  const int bm = swz / 6;
  const int bn = swz - bm * 6;
  const size_t m0 = (size_t)bm * 128;
  const int n0 = bn * 128;

  const int ra = tid >> 2;          // row 0..63 within half-tile
  const int ca = (tid & 3) * 8;     // 8 bf16 = 16B per thread
  const u16* ga = A  + (m0 + (size_t)ra) * K_LIN + ca;
  const u16* gb = Bw + (size_t)(n0 + ra) * K_LIN + ca;
  u16* lA = &As[wid * 512];         // wave-uniform base; HW adds lane*16B
  u16* lB = &Bs[wid * 512];

  const int l15 = lane & 15, l4 = lane >> 4;
  const u16* pAf = &As[(wm * 64 + l15) * 32 + l4 * 8];
  const u16* pBf = &Bs[(wn * 64 + l15) * 32 + l4 * 8];

  f32x4 acc[4][4] = {};

  for (int kt = 0; kt < 9; ++kt) {  // K = 288 = 9*32
    const int ko = kt * 32;
    gload16(ga + ko,               lA);
    gload16(ga + 64 * K_LIN + ko,  lA + 2048);
    gload16(gb + ko,               lB);
    gload16(gb + 64 * K_LIN + ko,  lB + 2048);
    __syncthreads();                 // drains vmcnt(0) -> tiles resident
    bf16x8 af[4], bfv[4];
#pragma unroll
    for (int i = 0; i < 4; ++i) af[i]  = *(const bf16x8*)(const void*)(pAf + i * 512);
#pragma unroll
    for (int i = 0; i < 4; ++i) bfv[i] = *(const bf16x8*)(const void*)(pBf + i * 512);
#pragma unroll
    for (int mi = 0; mi < 4; ++mi)
#pragma unroll
      for (int ni = 0; ni < 4; ++ni)
        acc[mi][ni] = __builtin_amdgcn_mfma_f32_16x16x32_bf16(af[mi], bfv[ni], acc[mi][ni], 0, 0, 0);
    __syncthreads();                 // protect LDS before next stage
  }

  float bv[4];
#pragma unroll
  for (int ni = 0; ni < 4; ++ni) bv[ni] = bias[n0 + wn * 64 + ni * 16 + l15];

#pragma unroll
  for (int mi = 0; mi < 4; ++mi) {
#pragma unroll
    for (int ni = 0; ni < 4; ++ni) {
      const int col = n0 + wn * 64 + ni * 16 + l15;
      if (col < N_LIN) {
#pragma unroll
        for (int r = 0; r < 4; ++r) {
          const size_t row = m0 + wm * 64 + mi * 16 + l4 * 4 + r;
          C[row * N_LIN + col] = acc[mi][ni][r] + bv[ni];
        }
      }
    }
  }
}

extern "C" void kernel_launch(void* const* d_in, const int* in_sizes, int n_in,
                              void* d_out, int out_size, void* d_ws, size_t ws_size,
                              hipStream_t stream) {
  const float* x    = (const float*)d_in[0];
  const float* Wih  = (const float*)d_in[1];
  const float* Whh  = (const float*)d_in[2];
  const float* bih  = (const float*)d_in[3];
  const float* bhh  = (const float*)d_in[4];
  const float* Wlin = (const float*)d_in[5];
  const float* blin = (const float*)d_in[6];
  float* out = (float*)d_out;

  // workspace layout (19.3 MB): hs bf16 [32768][288] | Bw bf16 [768][288] | bias f32 [768]
  u16* hs = (u16*)d_ws;
  u16* Bw = (u16*)((char*)d_ws + (size_t)B_TOT * K_LIN * 2);
  float* biasp = (float*)((char*)d_ws + (size_t)B_TOT * K_LIN * 2 + (size_t)N_PAD * K_LIN * 2);

  convert_kernel<<<(N_PAD * K_LIN + 255) / 256, 256, 0, stream>>>(Wlin, blin, Bw, biasp);
  lstm_kernel<<<(B_TOT * 4) / 256, 256, 0, stream>>>(x, Wih, Whh, bih, bhh, hs);
  gemm_kernel<<<(B_TOT / 128) * (N_PAD / 128), 256, 0, stream>>>(hs, Bw, biasp, out);
}

// Round 5
// 69.413 us; speedup vs baseline: 1.0268x; 1.0030x over previous
//
#include <hip/hip_runtime.h>
#include <stdint.h>

typedef unsigned short u16;
typedef unsigned int u32;
typedef __attribute__((ext_vector_type(8))) __bf16 bf16x8;
typedef __attribute__((ext_vector_type(4))) float f32x4;

#define B_TOT   32768
#define T_SEQ   96
#define D_IN    7
#define K_LIN   288   // H*T
#define N_LIN   672   // O*T
#define N_PAD   768   // padded N so 128-wide tiles need no load guards

#define LOG2E      1.4426950408889634f
#define TWO_LOG2E  2.8853900817779268f

// ---------- helpers ----------
__device__ __forceinline__ u16 f2bf(float f) {
  u32 u = __builtin_bit_cast(u32, f);
  u += 0x7fffu + ((u >> 16) & 1u);   // RNE; inputs finite
  return (u16)(u >> 16);
}
// z' = z*log2e prescaled:  sigmoid(z) = rcp(1 + 2^(-z'))
__device__ __forceinline__ float sig2(float zp) {
  return __builtin_amdgcn_rcpf(1.0f + __builtin_amdgcn_exp2f(-zp));
}
// z'' = 2*log2e*z prescaled:  tanh(z) = 1 - 2*rcp(1 + 2^(z''))
__device__ __forceinline__ float tanh2(float zpp) {
  return 1.0f - 2.0f * __builtin_amdgcn_rcpf(1.0f + __builtin_amdgcn_exp2f(zpp));
}
// broadcast quad-lane Q's value to all 4 lanes of the quad (DPP, full-rate VALU)
template<int Q>
__device__ __forceinline__ float qbcast(float v) {
  int i = __builtin_bit_cast(int, v);
  i = __builtin_amdgcn_update_dpp(0, i, Q * 0x55, 0xF, 0xF, true);
  return __builtin_bit_cast(float, i);
}

// ---------- kernel 1: pad/convert W_lin -> bf16, k-permuted to j-major ----------
// Bw[n][j*96+t] = Wlin[n][t*3+j]  (matches lstm's j-major hs layout)
__global__ __launch_bounds__(256) void convert_kernel(
    const float* __restrict__ Wlin, const float* __restrict__ blin,
    u16* __restrict__ Bw, float* __restrict__ biasp)
{
  int i = blockIdx.x * 256 + threadIdx.x;
  if (i < N_PAD * K_LIN) {
    int n = i / K_LIN;
    int kk = i - n * K_LIN;
    int jm = kk / T_SEQ;          // 0..2
    int tm = kk - jm * T_SEQ;     // 0..95
    Bw[i] = f2bf((n < N_LIN) ? Wlin[n * K_LIN + tm * 3 + jm] : 0.0f);
  }
  if (i < N_PAD) biasp[i] = (i < N_LIN) ? blin[i] : 0.0f;
}

// ---------- kernel 2: LSTM, 4 lanes per chain (lane q -> unit j=min(q,2)) ----------
__device__ __forceinline__ void chunk4(
    const float* xc,
    float& h0, float& h1, float& h2, float& c,
    const float (&wih)[4][7], const float (&whh)[4][3], const float (&bias)[4],
    float* hv_out)
{
  // h-independent pre-activations for all 4 steps: 112 independent FMAs of ILP
  float zx[4][4];
#pragma unroll
  for (int s = 0; s < 4; ++s) {
#pragma unroll
    for (int G = 0; G < 4; ++G) {
      float a = bias[G];
#pragma unroll
      for (int k = 0; k < 7; ++k) a = fmaf(xc[s * 7 + k], wih[G][k], a);
      zx[s][G] = a;
    }
  }
#pragma unroll
  for (int s = 0; s < 4; ++s) {
    float zi = fmaf(h2, whh[0][2], fmaf(h1, whh[0][1], fmaf(h0, whh[0][0], zx[s][0])));
    float zf = fmaf(h2, whh[1][2], fmaf(h1, whh[1][1], fmaf(h0, whh[1][0], zx[s][1])));
    float zg = fmaf(h2, whh[2][2], fmaf(h1, whh[2][1], fmaf(h0, whh[2][0], zx[s][2])));
    float zo = fmaf(h2, whh[3][2], fmaf(h1, whh[3][1], fmaf(h0, whh[3][0], zx[s][3])));
    float ig = sig2(zi);
    float fg = sig2(zf);
    float gg = tanh2(zg);                 // g-row prescaled by 2*log2e
    float og = sig2(zo);
    c = fmaf(fg, c, ig * gg);
    float hv = og * tanh2(c * TWO_LOG2E);
    hv_out[s] = hv;
    h0 = qbcast<0>(hv);
    h1 = qbcast<1>(hv);
    h2 = qbcast<2>(hv);
  }
}

// waves_per_eu(2,2): grid is exactly 2 waves/SIMD, so cap=2 is free and the
// RA budget becomes 256 VGPR. Rounds 2-3 showed the default heuristic pins
// VGPR=60 and sinks weight ds_reads into the serial chain (55us, WRITE 56MB
// scratch). Weights are additionally asm-pinned below so they CANNOT be
// rematerialized from LDS inside the loop.
__global__ __attribute__((amdgpu_flat_work_group_size(256, 256), amdgpu_waves_per_eu(2, 2)))
void lstm_kernel(
    const float* __restrict__ x,
    const float* __restrict__ Wih, const float* __restrict__ Whh,
    const float* __restrict__ bih, const float* __restrict__ bhh,
    u16* __restrict__ hs)
{
  __shared__ float sW[132];
  const int tid = threadIdx.x;
  for (int i = tid; i < 132; i += 256) {
    float v; int row;
    if (i < 84)       { v = Wih[i];       row = i / 7; }
    else if (i < 120) { v = Whh[i - 84];  row = (i - 84) / 3; }
    else              { v = bih[i - 120] + bhh[i - 120]; row = i - 120; }
    const int G = row / 3;                 // gate 0..3 (i,f,g,o)
    sW[i] = v * ((G == 2) ? TWO_LOG2E : LOG2E);
  }
  __syncthreads();

  const int j  = tid & 3;
  const int jj = (j < 3) ? j : 2;   // lane 3 mirrors lane 2 (never stores)

  // per-lane weights: 4 gates (i,f,g,o) for unit jj
  float wih[4][7], whh[4][3], bias[4];
#pragma unroll
  for (int G = 0; G < 4; ++G) {
    const int row = G * 3 + jj;
#pragma unroll
    for (int k = 0; k < 7; ++k) wih[G][k] = sW[row * 7 + k];
#pragma unroll
    for (int m = 0; m < 3; ++m) whh[G][m] = sW[84 + row * 3 + m];
    bias[G] = sW[120 + row];
  }
  // pin in VGPRs: opaque asm makes remat/sinking of the LDS loads impossible
#pragma unroll
  for (int G = 0; G < 4; ++G) {
#pragma unroll
    for (int k = 0; k < 7; ++k) asm volatile("" : "+v"(wih[G][k]));
#pragma unroll
    for (int m = 0; m < 3; ++m) asm volatile("" : "+v"(whh[G][m]));
    asm volatile("" : "+v"(bias[G]));
  }

  const int b = (blockIdx.x * 256 + tid) >> 2;
  const float4* __restrict__ xr = (const float4*)(x + (size_t)b * (T_SEQ * D_IN));
  u16* __restrict__ hrow = hs + (size_t)b * K_LIN + jj * T_SEQ;  // j-major

  float h0 = 0.f, h1 = 0.f, h2 = 0.f, c = 0.f;
  float xa[28] __attribute__((aligned(16)));   // 4 timesteps
  float xb[28] __attribute__((aligned(16)));
  float hv8[8];                                 // 8 steps of this lane's h, f32

#pragma unroll
  for (int q = 0; q < 7; ++q) ((float4*)xa)[q] = xr[q];

#pragma unroll 1
  for (int g8 = 0; g8 < 12; ++g8) {            // 8 steps per iter
#pragma unroll
    for (int q = 0; q < 7; ++q) ((float4*)xb)[q] = xr[(2 * g8 + 1) * 7 + q];
    chunk4(xa, h0, h1, h2, c, wih, whh, bias, hv8);
    if (g8 < 11) {
#pragma unroll
      for (int q = 0; q < 7; ++q) ((float4*)xa)[q] = xr[(2 * g8 + 2) * 7 + q];
    }
    chunk4(xb, h0, h1, h2, c, wih, whh, bias, hv8 + 4);
    if (j < 3) {
      u32 w0, w1, w2, w3;
      asm("v_cvt_pk_bf16_f32 %0, %1, %2" : "=v"(w0) : "v"(hv8[0]), "v"(hv8[1]));
      asm("v_cvt_pk_bf16_f32 %0, %1, %2" : "=v"(w1) : "v"(hv8[2]), "v"(hv8[3]));
      asm("v_cvt_pk_bf16_f32 %0, %1, %2" : "=v"(w2) : "v"(hv8[4]), "v"(hv8[5]));
      asm("v_cvt_pk_bf16_f32 %0, %1, %2" : "=v"(w3) : "v"(hv8[6]), "v"(hv8[7]));
      uint4 pkv; pkv.x = w0; pkv.y = w1; pkv.z = w2; pkv.w = w3;
      *(uint4*)(hrow + g8 * 8) = pkv;          // 16B, contiguous in t (j-major)
    }
  }
}

// ---------- kernel 3: out = hs(bf16)[32768x288] x Bw^T(bf16)[768x288] + bias ----------
__device__ __forceinline__ void gload16(const u16* g, u16* l) {
  __builtin_amdgcn_global_load_lds(
      (const __attribute__((address_space(1))) void*)g,
      (__attribute__((address_space(3))) void*)l, 16, 0, 0);
}

__global__ __launch_bounds__(256) void gemm_kernel(
    const u16* __restrict__ A, const u16* __restrict__ Bw,
    const float* __restrict__ bias, float* __restrict__ C)
{
  __shared__ u16 As[128 * 32];   // 8KB, row-major [128][32]
  __shared__ u16 Bs[128 * 32];
  const int tid  = threadIdx.x;
  const int lane = tid & 63;
  const int wid  = tid >> 6;
  const int wm = wid >> 1, wn = wid & 1;   // 2x2 waves of 64x64

  // XCD-bijective swizzle (1536 % 8 == 0); consecutive swz share A row-panel
  int bx = blockIdx.x;
  int swz = (bx & 7) * 192 + (bx >> 3);
  const int bm = swz / 6;
  const int bn = swz - bm * 6;
  const size_t m0 = (size_t)bm * 128;
  const int n0 = bn * 128;

  const int ra = tid >> 2;          // row 0..63 within half-tile
  const int ca = (tid & 3) * 8;     // 8 bf16 = 16B per thread
  const u16* ga = A  + (m0 + (size_t)ra) * K_LIN + ca;
  const u16* gb = Bw + (size_t)(n0 + ra) * K_LIN + ca;
  u16* lA = &As[wid * 512];         // wave-uniform base; HW adds lane*16B
  u16* lB = &Bs[wid * 512];

  const int l15 = lane & 15, l4 = lane >> 4;
  const u16* pAf = &As[(wm * 64 + l15) * 32 + l4 * 8];
  const u16* pBf = &Bs[(wn * 64 + l15) * 32 + l4 * 8];

  f32x4 acc[4][4] = {};

  for (int kt = 0; kt < 9; ++kt) {  // K = 288 = 9*32
    const int ko = kt * 32;
    gload16(ga + ko,               lA);
    gload16(ga + 64 * K_LIN + ko,  lA + 2048);
    gload16(gb + ko,               lB);
    gload16(gb + 64 * K_LIN + ko,  lB + 2048);
    __syncthreads();                 // drains vmcnt(0) -> tiles resident
    bf16x8 af[4], bfv[4];
#pragma unroll
    for (int i = 0; i < 4; ++i) af[i]  = *(const bf16x8*)(const void*)(pAf + i * 512);
#pragma unroll
    for (int i = 0; i < 4; ++i) bfv[i] = *(const bf16x8*)(const void*)(pBf + i * 512);
#pragma unroll
    for (int mi = 0; mi < 4; ++mi)
#pragma unroll
      for (int ni = 0; ni < 4; ++ni)
        acc[mi][ni] = __builtin_amdgcn_mfma_f32_16x16x32_bf16(af[mi], bfv[ni], acc[mi][ni], 0, 0, 0);
    __syncthreads();                 // protect LDS before next stage
  }

  float bv[4];
#pragma unroll
  for (int ni = 0; ni < 4; ++ni) bv[ni] = bias[n0 + wn * 64 + ni * 16 + l15];

#pragma unroll
  for (int mi = 0; mi < 4; ++mi) {
#pragma unroll
    for (int ni = 0; ni < 4; ++ni) {
      const int col = n0 + wn * 64 + ni * 16 + l15;
      if (col < N_LIN) {
#pragma unroll
        for (int r = 0; r < 4; ++r) {
          const size_t row = m0 + wm * 64 + mi * 16 + l4 * 4 + r;
          C[row * N_LIN + col] = acc[mi][ni][r] + bv[ni];
        }
      }
    }
  }
}

extern "C" void kernel_launch(void* const* d_in, const int* in_sizes, int n_in,
                              void* d_out, int out_size, void* d_ws, size_t ws_size,
                              hipStream_t stream) {
  const float* x    = (const float*)d_in[0];
  const float* Wih  = (const float*)d_in[1];
  const float* Whh  = (const float*)d_in[2];
  const float* bih  = (const float*)d_in[3];
  const float* bhh  = (const float*)d_in[4];
  const float* Wlin = (const float*)d_in[5];
  const float* blin = (const float*)d_in[6];
  float* out = (float*)d_out;

  // workspace layout (19.3 MB): hs bf16 [32768][288] | Bw bf16 [768][288] | bias f32 [768]
  u16* hs = (u16*)d_ws;
  u16* Bw = (u16*)((char*)d_ws + (size_t)B_TOT * K_LIN * 2);
  float* biasp = (float*)((char*)d_ws + (size_t)B_TOT * K_LIN * 2 + (size_t)N_PAD * K_LIN * 2);

  convert_kernel<<<(N_PAD * K_LIN + 255) / 256, 256, 0, stream>>>(Wlin, blin, Bw, biasp);
  lstm_kernel<<<(B_TOT * 4) / 256, 256, 0, stream>>>(x, Wih, Whh, bih, bhh, hs);
  gemm_kernel<<<(B_TOT / 128) * (N_PAD / 128), 256, 0, stream>>>(hs, Bw, biasp, out);
}

// Round 6
// 68.778 us; speedup vs baseline: 1.0363x; 1.0092x over previous
//
#include <hip/hip_runtime.h>
#include <stdint.h>

typedef unsigned short u16;
typedef unsigned int u32;
typedef __attribute__((ext_vector_type(8))) __bf16 bf16x8;
typedef __attribute__((ext_vector_type(4))) float f32x4;
typedef __attribute__((ext_vector_type(4))) float float4v;

#define B_TOT   32768
#define T_SEQ   96
#define D_IN    7
#define K_LIN   288   // H*T
#define N_LIN   672   // O*T
#define N_PAD   768   // padded N so 128-wide tiles need no load guards

#define LOG2E      1.4426950408889634f
#define TWO_LOG2E  2.8853900817779268f

// ---------- helpers ----------
__device__ __forceinline__ u16 f2bf(float f) {
  u32 u = __builtin_bit_cast(u32, f);
  u += 0x7fffu + ((u >> 16) & 1u);   // RNE; inputs finite
  return (u16)(u >> 16);
}
// z' = z*log2e prescaled:  sigmoid(z) = rcp(1 + 2^(-z'))
__device__ __forceinline__ float sig2(float zp) {
  return __builtin_amdgcn_rcpf(1.0f + __builtin_amdgcn_exp2f(-zp));
}
// z'' = 2*log2e*z prescaled:  tanh(z) = 1 - 2*rcp(1 + 2^(z''))
__device__ __forceinline__ float tanh2(float zpp) {
  return 1.0f - 2.0f * __builtin_amdgcn_rcpf(1.0f + __builtin_amdgcn_exp2f(zpp));
}
// broadcast quad-lane Q's value to all 4 lanes of the quad (DPP, full-rate VALU)
template<int Q>
__device__ __forceinline__ float qbcast(float v) {
  int i = __builtin_bit_cast(int, v);
  i = __builtin_amdgcn_update_dpp(0, i, Q * 0x55, 0xF, 0xF, true);
  return __builtin_bit_cast(float, i);
}

// inline-asm x loader: forces the dest regs live (RA cannot sink/refetch),
// letting US schedule the double-buffer with counted vmcnt waits.
#define GLOAD4(dst, base, OFFSTR) \
  asm volatile("global_load_dwordx4 %0, %1, off offset:" OFFSTR \
               : "=v"(dst) : "v"(base))
#define ISSUE7(v0,v1,v2,v3,v4,v5,v6, base) do { \
  GLOAD4(v0, base, "0");  GLOAD4(v1, base, "16"); GLOAD4(v2, base, "32"); \
  GLOAD4(v3, base, "48"); GLOAD4(v4, base, "64"); GLOAD4(v5, base, "80"); \
  GLOAD4(v6, base, "96"); } while (0)
// wait until <=N vmem ops outstanding; "+v" redefines the buffer so every
// consumer data-depends on this asm (cannot be hoisted above it).
#define WAIT7(v0,v1,v2,v3,v4,v5,v6) \
  asm volatile("s_waitcnt vmcnt(7)" : "+v"(v0),"+v"(v1),"+v"(v2),"+v"(v3),"+v"(v4),"+v"(v5),"+v"(v6))
#define WAIT0(v0,v1,v2,v3,v4,v5,v6) \
  asm volatile("s_waitcnt vmcnt(0)" : "+v"(v0),"+v"(v1),"+v"(v2),"+v"(v3),"+v"(v4),"+v"(v5),"+v"(v6))

// ---------- kernel 1: pad/convert W_lin -> bf16, k-permuted to j-major ----------
// Bw[n][j*96+t] = Wlin[n][t*3+j]  (matches lstm's j-major hs layout)
__global__ __launch_bounds__(256) void convert_kernel(
    const float* __restrict__ Wlin, const float* __restrict__ blin,
    u16* __restrict__ Bw, float* __restrict__ biasp)
{
  int i = blockIdx.x * 256 + threadIdx.x;
  if (i < N_PAD * K_LIN) {
    int n = i / K_LIN;
    int kk = i - n * K_LIN;
    int jm = kk / T_SEQ;          // 0..2
    int tm = kk - jm * T_SEQ;     // 0..95
    Bw[i] = f2bf((n < N_LIN) ? Wlin[n * K_LIN + tm * 3 + jm] : 0.0f);
  }
  if (i < N_PAD) biasp[i] = (i < N_LIN) ? blin[i] : 0.0f;
}

// ---------- kernel 2: LSTM, 4 lanes per chain (lane q -> unit j=min(q,2)) ----------
__device__ __forceinline__ void chunk4(
    const float4v (&xs)[7],
    float& h0, float& h1, float& h2, float& c,
    const float (&wih)[4][7], const float (&whh)[4][3], const float (&bias)[4],
    float* hv_out)
{
  // h-independent pre-activations for all 4 steps: 112 independent FMAs of ILP
  float zx[4][4];
#pragma unroll
  for (int s = 0; s < 4; ++s) {
#pragma unroll
    for (int G = 0; G < 4; ++G) {
      float a = bias[G];
#pragma unroll
      for (int k = 0; k < 7; ++k) {
        const int f = s * 7 + k;
        a = fmaf(xs[f >> 2][f & 3], wih[G][k], a);
      }
      zx[s][G] = a;
    }
  }
#pragma unroll
  for (int s = 0; s < 4; ++s) {
    float zi = fmaf(h2, whh[0][2], fmaf(h1, whh[0][1], fmaf(h0, whh[0][0], zx[s][0])));
    float zf = fmaf(h2, whh[1][2], fmaf(h1, whh[1][1], fmaf(h0, whh[1][0], zx[s][1])));
    float zg = fmaf(h2, whh[2][2], fmaf(h1, whh[2][1], fmaf(h0, whh[2][0], zx[s][2])));
    float zo = fmaf(h2, whh[3][2], fmaf(h1, whh[3][1], fmaf(h0, whh[3][0], zx[s][3])));
    float ig = sig2(zi);
    float fg = sig2(zf);
    float gg = tanh2(zg);                 // g-row prescaled by 2*log2e
    float og = sig2(zo);
    c = fmaf(fg, c, ig * gg);
    float hv = og * tanh2(c * TWO_LOG2E);
    hv_out[s] = hv;
    h0 = qbcast<0>(hv);
    h1 = qbcast<1>(hv);
    h2 = qbcast<2>(hv);
  }
}

__global__ __attribute__((amdgpu_flat_work_group_size(256, 256), amdgpu_waves_per_eu(2, 2)))
void lstm_kernel(
    const float* __restrict__ x,
    const float* __restrict__ Wih, const float* __restrict__ Whh,
    const float* __restrict__ bih, const float* __restrict__ bhh,
    u16* __restrict__ hs)
{
  __shared__ float sW[132];
  const int tid = threadIdx.x;
  for (int i = tid; i < 132; i += 256) {
    float v; int row;
    if (i < 84)       { v = Wih[i];       row = i / 7; }
    else if (i < 120) { v = Whh[i - 84];  row = (i - 84) / 3; }
    else              { v = bih[i - 120] + bhh[i - 120]; row = i - 120; }
    const int G = row / 3;                 // gate 0..3 (i,f,g,o)
    sW[i] = v * ((G == 2) ? TWO_LOG2E : LOG2E);
  }
  __syncthreads();

  const int j  = tid & 3;
  const int jj = (j < 3) ? j : 2;   // lane 3 mirrors lane 2 (never stores)

  // per-lane weights: 4 gates (i,f,g,o) for unit jj
  float wih[4][7], whh[4][3], bias[4];
#pragma unroll
  for (int G = 0; G < 4; ++G) {
    const int row = G * 3 + jj;
#pragma unroll
    for (int k = 0; k < 7; ++k) wih[G][k] = sW[row * 7 + k];
#pragma unroll
    for (int m = 0; m < 3; ++m) whh[G][m] = sW[84 + row * 3 + m];
    bias[G] = sW[120 + row];
  }
  // pin weights in VGPRs: opaque asm forbids remat/sinking of the LDS loads
#pragma unroll
  for (int G = 0; G < 4; ++G) {
#pragma unroll
    for (int k = 0; k < 7; ++k) asm volatile("" : "+v"(wih[G][k]));
#pragma unroll
    for (int m = 0; m < 3; ++m) asm volatile("" : "+v"(whh[G][m]));
    asm volatile("" : "+v"(bias[G]));
  }

  const int b = (blockIdx.x * 256 + tid) >> 2;
  const float* __restrict__ row = x + (size_t)b * (T_SEQ * D_IN);
  u16* __restrict__ hrow = hs + (size_t)b * K_LIN + jj * T_SEQ;  // j-major

  float h0 = 0.f, h1 = 0.f, h2 = 0.f, c = 0.f;
  float hv8[8];

  // double-buffered 4-step x chunks in named regs, hand-scheduled vmcnt.
  float4v a0, a1, a2, a3, a4, a5, a6;   // chunk 2*g8
  float4v b0, b1, b2, b3, b4, b5, b6;   // chunk 2*g8+1
  ISSUE7(a0,a1,a2,a3,a4,a5,a6, row);            // chunk 0
  const float* px = row + 28;                    // next chunk to load

#pragma unroll 1
  for (int g8 = 0; g8 < 11; ++g8) {
    ISSUE7(b0,b1,b2,b3,b4,b5,b6, px);           // chunk 2g8+1
    WAIT7(a0,a1,a2,a3,a4,a5,a6);                // A done (B still in flight)
    {
      float4v xs[7] = {a0,a1,a2,a3,a4,a5,a6};
      chunk4(xs, h0, h1, h2, c, wih, whh, bias, hv8);
    }
    ISSUE7(a0,a1,a2,a3,a4,a5,a6, px + 28);      // chunk 2g8+2
    px += 56;
    WAIT7(b0,b1,b2,b3,b4,b5,b6);                // B done (A' still in flight)
    {
      float4v xs[7] = {b0,b1,b2,b3,b4,b5,b6};
      chunk4(xs, h0, h1, h2, c, wih, whh, bias, hv8 + 4);
    }
    if (j < 3) {
      u32 w0, w1, w2, w3;
      asm("v_cvt_pk_bf16_f32 %0, %1, %2" : "=v"(w0) : "v"(hv8[0]), "v"(hv8[1]));
      asm("v_cvt_pk_bf16_f32 %0, %1, %2" : "=v"(w1) : "v"(hv8[2]), "v"(hv8[3]));
      asm("v_cvt_pk_bf16_f32 %0, %1, %2" : "=v"(w2) : "v"(hv8[4]), "v"(hv8[5]));
      asm("v_cvt_pk_bf16_f32 %0, %1, %2" : "=v"(w3) : "v"(hv8[6]), "v"(hv8[7]));
      uint4 pkv; pkv.x = w0; pkv.y = w1; pkv.z = w2; pkv.w = w3;
      *(uint4*)(hrow + g8 * 8) = pkv;           // 16B, contiguous in t (j-major)
    }
  }
  // peeled g8 = 11: chunk 22 already in flight as A; load chunk 23 as B
  ISSUE7(b0,b1,b2,b3,b4,b5,b6, px);
  WAIT7(a0,a1,a2,a3,a4,a5,a6);
  {
    float4v xs[7] = {a0,a1,a2,a3,a4,a5,a6};
    chunk4(xs, h0, h1, h2, c, wih, whh, bias, hv8);
  }
  WAIT0(b0,b1,b2,b3,b4,b5,b6);
  {
    float4v xs[7] = {b0,b1,b2,b3,b4,b5,b6};
    chunk4(xs, h0, h1, h2, c, wih, whh, bias, hv8 + 4);
  }
  if (j < 3) {
    u32 w0, w1, w2, w3;
    asm("v_cvt_pk_bf16_f32 %0, %1, %2" : "=v"(w0) : "v"(hv8[0]), "v"(hv8[1]));
    asm("v_cvt_pk_bf16_f32 %0, %1, %2" : "=v"(w1) : "v"(hv8[2]), "v"(hv8[3]));
    asm("v_cvt_pk_bf16_f32 %0, %1, %2" : "=v"(w2) : "v"(hv8[4]), "v"(hv8[5]));
    asm("v_cvt_pk_bf16_f32 %0, %1, %2" : "=v"(w3) : "v"(hv8[6]), "v"(hv8[7]));
    uint4 pkv; pkv.x = w0; pkv.y = w1; pkv.z = w2; pkv.w = w3;
    *(uint4*)(hrow + 11 * 8) = pkv;
  }
}

// ---------- kernel 3: out = hs(bf16)[32768x288] x Bw^T(bf16)[768x288] + bias ----------
__device__ __forceinline__ void gload16(const u16* g, u16* l) {
  __builtin_amdgcn_global_load_lds(
      (const __attribute__((address_space(1))) void*)g,
      (__attribute__((address_space(3))) void*)l, 16, 0, 0);
}

__global__ __launch_bounds__(256) void gemm_kernel(
    const u16* __restrict__ A, const u16* __restrict__ Bw,
    const float* __restrict__ bias, float* __restrict__ C)
{
  __shared__ u16 As[128 * 32];   // 8KB, row-major [128][32]
  __shared__ u16 Bs[128 * 32];
  const int tid  = threadIdx.x;
  const int lane = tid & 63;
  const int wid  = tid >> 6;
  const int wm = wid >> 1, wn = wid & 1;   // 2x2 waves of 64x64

  // XCD-bijective swizzle (1536 % 8 == 0); consecutive swz share A row-panel
  int bx = blockIdx.x;
  int swz = (bx & 7) * 192 + (bx >> 3);
  const int bm = swz / 6;
  const int bn = swz - bm * 6;
  const size_t m0 = (size_t)bm * 128;
  const int n0 = bn * 128;

  const int ra = tid >> 2;          // row 0..63 within half-tile
  const int ca = (tid & 3) * 8;     // 8 bf16 = 16B per thread
  const u16* ga = A  + (m0 + (size_t)ra) * K_LIN + ca;
  const u16* gb = Bw + (size_t)(n0 + ra) * K_LIN + ca;
  u16* lA = &As[wid * 512];         // wave-uniform base; HW adds lane*16B
  u16* lB = &Bs[wid * 512];

  const int l15 = lane & 15, l4 = lane >> 4;
  const u16* pAf = &As[(wm * 64 + l15) * 32 + l4 * 8];
  const u16* pBf = &Bs[(wn * 64 + l15) * 32 + l4 * 8];

  f32x4 acc[4][4] = {};

  for (int kt = 0; kt < 9; ++kt) {  // K = 288 = 9*32
    const int ko = kt * 32;
    gload16(ga + ko,               lA);
    gload16(ga + 64 * K_LIN + ko,  lA + 2048);
    gload16(gb + ko,               lB);
    gload16(gb + 64 * K_LIN + ko,  lB + 2048);
    __syncthreads();                 // drains vmcnt(0) -> tiles resident
    bf16x8 af[4], bfv[4];
#pragma unroll
    for (int i = 0; i < 4; ++i) af[i]  = *(const bf16x8*)(const void*)(pAf + i * 512);
#pragma unroll
    for (int i = 0; i < 4; ++i) bfv[i] = *(const bf16x8*)(const void*)(pBf + i * 512);
#pragma unroll
    for (int mi = 0; mi < 4; ++mi)
#pragma unroll
      for (int ni = 0; ni < 4; ++ni)
        acc[mi][ni] = __builtin_amdgcn_mfma_f32_16x16x32_bf16(af[mi], bfv[ni], acc[mi][ni], 0, 0, 0);
    __syncthreads();                 // protect LDS before next stage
  }

  float bv[4];
#pragma unroll
  for (int ni = 0; ni < 4; ++ni) bv[ni] = bias[n0 + wn * 64 + ni * 16 + l15];

#pragma unroll
  for (int mi = 0; mi < 4; ++mi) {
#pragma unroll
    for (int ni = 0; ni < 4; ++ni) {
      const int col = n0 + wn * 64 + ni * 16 + l15;
      if (col < N_LIN) {
#pragma unroll
        for (int r = 0; r < 4; ++r) {
          const size_t row = m0 + wm * 64 + mi * 16 + l4 * 4 + r;
          C[row * N_LIN + col] = acc[mi][ni][r] + bv[ni];
        }
      }
    }
  }
}

extern "C" void kernel_launch(void* const* d_in, const int* in_sizes, int n_in,
                              void* d_out, int out_size, void* d_ws, size_t ws_size,
                              hipStream_t stream) {
  const float* x    = (const float*)d_in[0];
  const float* Wih  = (const float*)d_in[1];
  const float* Whh  = (const float*)d_in[2];
  const float* bih  = (const float*)d_in[3];
  const float* bhh  = (const float*)d_in[4];
  const float* Wlin = (const float*)d_in[5];
  const float* blin = (const float*)d_in[6];
  float* out = (float*)d_out;

  // workspace layout (19.3 MB): hs bf16 [32768][288] | Bw bf16 [768][288] | bias f32 [768]
  u16* hs = (u16*)d_ws;
  u16* Bw = (u16*)((char*)d_ws + (size_t)B_TOT * K_LIN * 2);
  float* biasp = (float*)((char*)d_ws + (size_t)B_TOT * K_LIN * 2 + (size_t)N_PAD * K_LIN * 2);

  convert_kernel<<<(N_PAD * K_LIN + 255) / 256, 256, 0, stream>>>(Wlin, blin, Bw, biasp);
  lstm_kernel<<<(B_TOT * 4) / 256, 256, 0, stream>>>(x, Wih, Whh, bih, bhh, hs);
  gemm_kernel<<<(B_TOT / 128) * (N_PAD / 128), 256, 0, stream>>>(hs, Bw, biasp, out);
}